// Round 3
// baseline (529.464 us; speedup 1.0000x reference)
//
#include <hip/hip_runtime.h>

#define PAD   4
#define DD    9
#define ND    81
#define BB    4
#define CCH   256
#define HH_   128
#define WW_   224
#define TH    8
#define TW    32
#define NTILES 448               // 7 wtiles * 16 htiles * 4 batch
#define PLANE  (HH_*WW_)         // 28672

__global__ __launch_bounds__(128)
void corr_kernel(const float* __restrict__ first,
                 const float* __restrict__ second,
                 const float* __restrict__ zws,    // >=256 B of zeros in d_ws
                 float* __restrict__ out)
{
    const int bx   = blockIdx.x;
    const int tile = bx % NTILES;        // stride-448 dy-partners share XCD (448%8==0)
    const int dy   = bx / NTILES;        // 0..8
    const int wt   = tile % 7;
    const int ht   = (tile / 7) % 16;
    const int b    = tile / 112;
    const int w0   = wt * TW, h0 = ht * TH;

    const int tid  = threadIdx.x;        // 0..127
    const int wv   = tid >> 6;           // wave 0: dx 0..3, wave 1: dx 4..8
    const int lane = tid & 63;
    const int wq   = lane & 7;           // column quad
    const int hh   = lane >> 3;          // row within tile

    const int h = h0 + hh;
    const int w = w0 + 4 * wq;
    const int srow  = h + dy - PAD;
    const bool valid = (srow >= 0) && (srow < HH_);
    const int srowc = valid ? srow : 0;  // clamped for address arith only

    const size_t plane = PLANE;
    const float* fbase = first  + (size_t)b * CCH * plane;
    const float* sbase = second + (size_t)b * CCH * plane;

    const float* fp = fbase + (size_t)h * WW_ + w;
    const float* sp = valid ? (sbase + (size_t)srowc * WW_ + w) : zws;
    const size_t sinc = valid ? plane : 0;

    const bool isL = (wq == 0), isR = (wq == 7);
    // wave 0 needs only the LEFT edge quad; wave 1 only the RIGHT edge quad
    const int  ecol   = wv ? (w0 + TW) : (w0 - PAD);
    const bool evalid = valid && (wv ? (isR && (w0 + TW) < WW_)
                                     : (isL && w0 > 0));
    const float* ep = evalid ? (sbase + (size_t)srowc * WW_ + ecol) : zws;
    const size_t einc = evalid ? plane : 0;

    const int li = (lane + 63) & 63;     // left neighbor
    const int ri = (lane + 1) & 63;      // right neighbor

    // window select folded into shuffle index:
    //  wave0 window t[0..7] = {a0..a3, m.x..m.w}  (s[0..7])
    //  wave1 window t[0..7] = {m.x..m.w, c0..c3}  (s[4..11])
    const int sel_lo = wv ? lane : li;
    const int sel_hi = wv ? ri   : lane;
    const bool rep_lo = (wv == 0) && isL;   // left-edge override of t[0..3]
    const bool rep_hi = (wv == 1) && isR;   // right-edge override of t[4..7]

    float acc[5][4];
    #pragma unroll
    for (int j = 0; j < 5; ++j) { acc[j][0]=0.f; acc[j][1]=0.f; acc[j][2]=0.f; acc[j][3]=0.f; }

    // prologue loads (channel 0)
    float4 f = *(const float4*)fp;  fp += plane;
    float4 m = *(const float4*)sp;  sp += sinc;
    float4 e = *(const float4*)ep;  ep += einc;

    for (int c = 0; c < CCH; ++c) {
        float4 fn, mn, en;
        if (c + 1 < CCH) {                       // prefetch next channel
            fn = *(const float4*)fp;  fp += plane;
            mn = *(const float4*)sp;  sp += sinc;
            en = *(const float4*)ep;  ep += einc;
        } else { fn = f; mn = m; en = e; }

        float t0 = __shfl(m.x, sel_lo), t1 = __shfl(m.y, sel_lo),
              t2 = __shfl(m.z, sel_lo), t3 = __shfl(m.w, sel_lo);
        float t4 = __shfl(m.x, sel_hi), t5 = __shfl(m.y, sel_hi),
              t6 = __shfl(m.z, sel_hi), t7 = __shfl(m.w, sel_hi);
        if (rep_lo) { t0 = e.x; t1 = e.y; t2 = e.z; t3 = e.w; }
        if (rep_hi) { t4 = e.x; t5 = e.y; t6 = e.z; t7 = e.w; }

        const float t[8]  = { t0, t1, t2, t3, t4, t5, t6, t7 };
        const float fv[4] = { f.x, f.y, f.z, f.w };

        // wave0: dx=j (j=0..4, j=4 unused); wave1: dx=4+j (j=0..4)
        #pragma unroll
        for (int j = 0; j < 5; ++j)
            #pragma unroll
            for (int px = 0; px < 4; ++px)
                acc[j][px] += fv[px] * t[j + px];

        f = fn; m = mn; e = en;
    }

    const float inv = 1.0f / (float)CCH;
    #pragma unroll
    for (int j = 0; j < 5; ++j) {
        if (wv == 0 && j == 4) continue;         // wave0 owns only dx 0..3
        const int d = dy * DD + wv * 4 + j;
        float4 o = make_float4(acc[j][0]*inv, acc[j][1]*inv,
                               acc[j][2]*inv, acc[j][3]*inv);
        *(float4*)&out[(((size_t)b * ND + d) * HH_ + h) * WW_ + w] = o;
    }
}

extern "C" void kernel_launch(void* const* d_in, const int* in_sizes, int n_in,
                              void* d_out, int out_size, void* d_ws, size_t ws_size,
                              hipStream_t stream) {
    const float* first  = (const float*)d_in[0];
    const float* second = (const float*)d_in[1];
    float* out = (float*)d_out;
    // 256-B zero pad for all out-of-bounds pointer redirection (branchless halo)
    hipMemsetAsync(d_ws, 0, 256, stream);
    dim3 grid(NTILES * DD);   // 4032 blocks, 2 waves each = 8064 waves (~31.5/CU)
    dim3 block(128);
    corr_kernel<<<grid, block, 0, stream>>>(first, second, (const float*)d_ws, out);
}

// Round 4
// 470.959 us; speedup vs baseline: 1.1242x; 1.1242x over previous
//
#include <hip/hip_runtime.h>

#define PAD   4
#define DD    9
#define ND    81
#define CCH   256
#define HH_   128
#define WW_   224
#define TH    8
#define TW    32
#define NTILES 448               // 7 wtiles * 16 htiles * 4 batch
#define PLANE  (HH_*WW_)         // 28672

__global__ __launch_bounds__(576)
void corr_kernel(const float* __restrict__ first,
                 const float* __restrict__ second,
                 const float* __restrict__ zws,    // >=256 B of zeros in d_ws
                 float* __restrict__ out)
{
    // One block per spatial tile; 9 waves = 9 dy values, co-resident on one CU
    // so their overlapping first/second reads hit L1 instead of thrashing LLC.
    const int bx   = blockIdx.x;                 // 0..447
    // XCD-chunked bijective swizzle (448 % 8 == 0): XCD k gets a contiguous
    // (b,ht) strip of 56 tiles -> vertical second-row overlap stays in its L2.
    const int tile = (bx & 7) * 56 + (bx >> 3);
    const int wt   = tile % 7;
    const int ht   = (tile / 7) % 16;
    const int b    = tile / 112;
    const int w0   = wt * TW, h0 = ht * TH;

    const int dy   = threadIdx.x >> 6;           // wave id = dy, 0..8
    const int lane = threadIdx.x & 63;
    const int wq   = lane & 7;                   // column quad
    const int hh   = lane >> 3;                  // row within tile

    const int h = h0 + hh;
    const int w = w0 + 4 * wq;
    const int srow  = h + dy - PAD;
    const bool valid = (srow >= 0) && (srow < HH_);
    const int srowc = valid ? srow : 0;          // clamped for address arith only

    const size_t plane = PLANE;
    const float* fbase = first  + (size_t)b * CCH * plane;
    const float* sbase = second + (size_t)b * CCH * plane;

    const float* fp = fbase + (size_t)h * WW_ + w;
    const float* sp = valid ? (sbase + (size_t)srowc * WW_ + w) : zws;
    const size_t sinc = valid ? plane : 0;

    const bool isL = (wq == 0), isR = (wq == 7);
    const int  ecol   = isL ? (w0 - PAD) : (w0 + TW);
    const bool evalid = valid && ((isL && w0 > 0) || (isR && (w0 + TW) < WW_));
    const float* ep = evalid ? (sbase + (size_t)srowc * WW_ + ecol) : zws;
    const size_t einc = evalid ? plane : 0;

    const int li = (lane + 63) & 63;             // left neighbor
    const int ri = (lane + 1) & 63;              // right neighbor

    float acc[DD][4];
    #pragma unroll
    for (int dx = 0; dx < DD; ++dx) { acc[dx][0]=0.f; acc[dx][1]=0.f; acc[dx][2]=0.f; acc[dx][3]=0.f; }

    // prologue loads (channel 0)
    float4 f = *(const float4*)fp;  fp += plane;
    float4 m = *(const float4*)sp;  sp += sinc;
    float4 e = *(const float4*)ep;  ep += einc;

    for (int c = 0; c < CCH; ++c) {
        float4 fn, mn, en;
        if (c + 1 < CCH) {                       // prefetch next channel
            fn = *(const float4*)fp;  fp += plane;
            mn = *(const float4*)sp;  sp += sinc;
            en = *(const float4*)ep;  ep += einc;
        } else { fn = f; mn = m; en = e; }

        // halo quads via cross-lane shuffle (no LDS tile)
        float a0 = __shfl(m.x, li), a1 = __shfl(m.y, li),
              a2 = __shfl(m.z, li), a3 = __shfl(m.w, li);
        float c0 = __shfl(m.x, ri), c1 = __shfl(m.y, ri),
              c2 = __shfl(m.z, ri), c3 = __shfl(m.w, ri);
        if (isL) { a0 = e.x; a1 = e.y; a2 = e.z; a3 = e.w; }
        if (isR) { c0 = e.x; c1 = e.y; c2 = e.z; c3 = e.w; }

        const float s[12] = { a0, a1, a2, a3,
                              m.x, m.y, m.z, m.w,
                              c0, c1, c2, c3 };
        const float fv[4] = { f.x, f.y, f.z, f.w };

        #pragma unroll
        for (int dx = 0; dx < DD; ++dx)
            #pragma unroll
            for (int px = 0; px < 4; ++px)
                acc[dx][px] += fv[px] * s[dx + px];

        f = fn; m = mn; e = en;

        // bound inter-wave drift so shared f/m lines stay L1-resident
        if ((c & 31) == 31) __syncthreads();
    }

    const float inv = 1.0f / (float)CCH;
    #pragma unroll
    for (int dx = 0; dx < DD; ++dx) {
        const int d = dy * DD + dx;
        float4 o = make_float4(acc[dx][0]*inv, acc[dx][1]*inv,
                               acc[dx][2]*inv, acc[dx][3]*inv);
        *(float4*)&out[(((size_t)b * ND + d) * HH_ + h) * WW_ + w] = o;
    }
}

extern "C" void kernel_launch(void* const* d_in, const int* in_sizes, int n_in,
                              void* d_out, int out_size, void* d_ws, size_t ws_size,
                              hipStream_t stream) {
    const float* first  = (const float*)d_in[0];
    const float* second = (const float*)d_in[1];
    float* out = (float*)d_out;
    // 256-B zero pad for all out-of-bounds pointer redirection (branchless halo)
    hipMemsetAsync(d_ws, 0, 256, stream);
    dim3 grid(NTILES);        // 448 blocks, 9 waves each (one dy per wave)
    dim3 block(9 * 64);
    corr_kernel<<<grid, block, 0, stream>>>(first, second, (const float*)d_ws, out);
}